// Round 16
// baseline (200.721 us; speedup 1.0000x reference)
//
#include <hip/hip_runtime.h>
#include <hip/hip_bf16.h>
#include <math.h>

#define BB 1024     // batch
#define LL 50       // sequence length
#define DD 256      // embedding dim
#define TWO_D 512
#define NN 40000    // nodes
#define DEG 12      // neighbors per node (adj_rows = repeat(arange(N), DEG))
#define NITER 50    // entmax bisect iterations

typedef __attribute__((ext_vector_type(8))) short short8;
typedef __attribute__((ext_vector_type(4))) float floatx4;

__device__ __forceinline__ float wave_sum64(float v) {
#pragma unroll
    for (int off = 32; off > 0; off >>= 1) v += __shfl_xor(v, off, 64);
    return v;
}
__device__ __forceinline__ float wave_max64(float v) {
#pragma unroll
    for (int off = 32; off > 0; off >>= 1) v = fmaxf(v, __shfl_xor(v, off, 64));
    return v;
}
__device__ __forceinline__ float bf2f(ushort u) {
    union { unsigned int i; float f; } c; c.i = ((unsigned int)u) << 16; return c.f;
}
__device__ __forceinline__ ushort f2bf(float f) {
    __hip_bfloat16 h = __float2bfloat16(f);
    return *(ushort*)&h;
}
__device__ __forceinline__ float hw_exp2(float x) { return __builtin_amdgcn_exp2f(x); }
__device__ __forceinline__ float hw_log2(float x) { return __builtin_amdgcn_logf(x); }

// ---------------- L1: wprep (+w1t fold) | mark ------------------------------
// No emb convert any more (conv reads fp32 directly).
// bid [0,512):   k = bid:
//   wcol = wf_w[:,k] staged to LDS (coalesced, one load/thread), then
//   Wc[k][n] = sum_d wcol[d]*at_w2[d][n] with 8 independent chains;
//   v[k] = dot(wcol, aw);  k<64: w1t cols;  k==0: bc, c0.
// bid [512,712): flags[items[i]] = 1 (no zero-init needed: !=1 only causes
//   extra conv work, never wrong values)
__global__ __launch_bounds__(256) void k_stage1(
    const int* __restrict__ items, int* __restrict__ flags,
    const float* __restrict__ wf_w, const float* __restrict__ wf_b,
    const float* __restrict__ at_w2, const float* __restrict__ at_bias,
    const float* __restrict__ aw, const float* __restrict__ ab,
    const float* __restrict__ at_w1,
    float* __restrict__ Wc, float* __restrict__ v,
    float* __restrict__ bc, float* __restrict__ c0,
    ushort* __restrict__ w1t)
{
    __shared__ float wcol[DD];
    __shared__ float wred[4];
    __shared__ ushort s_t[4][DD];
    int bid = blockIdx.x;
    int tid = threadIdx.x;

    if (bid < 512) {
        int k = bid;
        int lane = tid & 63, wv = tid >> 6;

        // stage wf_w column k: one strided load per thread, then LDS-resident
        wcol[tid] = wf_w[tid * TWO_D + k];
        __syncthreads();

        // 8 independent chains: 8 at_w2 loads in flight, wcol from LDS
        float a[8];
#pragma unroll
        for (int j = 0; j < 8; ++j) a[j] = 0.f;
#pragma unroll 4
        for (int d = 0; d < DD; d += 8) {
#pragma unroll
            for (int j = 0; j < 8; ++j)
                a[j] += wcol[d + j] * at_w2[(d + j) * DD + tid];
        }
        Wc[k * DD + tid] = ((a[0] + a[1]) + (a[2] + a[3]))
                         + ((a[4] + a[5]) + (a[6] + a[7]));

        float s1 = wcol[tid] * aw[tid];
        s1 = wave_sum64(s1);
        if (lane == 0) wred[wv] = s1;
        __syncthreads();
        if (tid == 0) v[k] = wred[0] + wred[1] + wred[2] + wred[3];

        if (k < 64) {
            // transpose 4 columns of at_w1: w1t[t][k0+j] = at_w1[k0+j][t]
            int k0 = k * 4;
#pragma unroll
            for (int j = 0; j < 4; ++j)
                s_t[j][tid] = f2bf(at_w1[(k0 + j) * DD + tid]);
            __syncthreads();
            ushort4 pk;
            pk.x = s_t[0][tid]; pk.y = s_t[1][tid];
            pk.z = s_t[2][tid]; pk.w = s_t[3][tid];
            *(ushort4*)(w1t + tid * DD + k0) = pk;
        }

        if (k == 0) {
            // stage wf_b into LDS (reuse wcol), then 8-chain bc loop
            __syncthreads();
            wcol[tid] = wf_b[tid];
            __syncthreads();
            float b[8];
#pragma unroll
            for (int j = 0; j < 8; ++j) b[j] = 0.f;
#pragma unroll 4
            for (int d = 0; d < DD; d += 8) {
#pragma unroll
                for (int j = 0; j < 8; ++j)
                    b[j] += wcol[d + j] * at_w2[(d + j) * DD + tid];
            }
            bc[tid] = at_bias[tid] + ((b[0] + b[1]) + (b[2] + b[3]))
                                   + ((b[4] + b[5]) + (b[6] + b[7]));
            float s2 = wcol[tid] * aw[tid];
            s2 = wave_sum64(s2);
            if (lane == 0) wred[wv] = s2;
            __syncthreads();
            if (tid == 0) c0[0] = wred[0] + wred[1] + wred[2] + wred[3] + ab[0];
        }
    } else {
        int i = (bid - 512) * 256 + tid;
        flags[items[i]] = 1;
    }
}

// ---------------- L2: t2 direct + alpha | conv (fp32 direct) ----------------
// t2a blocks FIRST (long per-block GEMV) so they overlap conv (R13 lesson).
// bid [0,1024): t2[b,n] = tgt[b,:]@Wc[:,n] + bc[n]; ntile==0 emits alpha
// bid [1024,11024): per-node conv from fp32 emb (one wave per node,
//                   skip unflagged), writes bf16 gbf
__global__ __launch_bounds__(256) void k_stage2(
    const float* __restrict__ emb, const int* __restrict__ adj_cols,
    const float* __restrict__ adj_vals, const int* __restrict__ flags,
    ushort* __restrict__ gbf,
    const float* __restrict__ tgt, const float* __restrict__ Wc,
    const float* __restrict__ bc, const float* __restrict__ v,
    const float* __restrict__ c0, float* __restrict__ t2,
    float* __restrict__ alpha)
{
    __shared__ float x_s[4 * TWO_D];
    int bid = blockIdx.x;
    int tid = threadIdx.x;
    int wv = tid >> 6, lane = tid & 63;

    if (bid < 1024) {
        int t = bid;
        int btile = t >> 2, ntile = t & 3;
        int b0 = btile * 4, n0 = ntile * 64;
        int j = wv;
        for (int i = tid; i < 4 * TWO_D; i += 256) x_s[i] = tgt[b0 * TWO_D + i];
        __syncthreads();

        float acc = bc[n0 + lane];
        const float* xr = x_s + j * TWO_D;
#pragma unroll 8
        for (int k = 0; k < TWO_D; ++k)
            acc += xr[k] * Wc[k * DD + n0 + lane];
        t2[(b0 + j) * DD + n0 + lane] = acc;

        if (ntile == 0) {
            float s = 0.f;
#pragma unroll
            for (int i = 0; i < 8; ++i) s += xr[lane + 64 * i] * v[lane + 64 * i];
            s = wave_sum64(s);
            if (lane == 0) {
                float a = 1.f + 1.f / (1.f + expf(-(s + c0[0])));
                if (a == 1.f) a = 1.00001f;
                alpha[b0 + j] = a;
            }
        }
    } else {
        int n = (bid - 1024) * 4 + wv;
        if (flags[n] != 1) return;
        int colv = 0; float valv = 0.f;
        if (lane < DEG) { colv = adj_cols[n * DEG + lane]; valv = adj_vals[n * DEG + lane]; }
        int cols[DEG]; float vals[DEG];
#pragma unroll
        for (int k = 0; k < DEG; ++k) {
            cols[k] = __shfl(colv, k, 64);
            vals[k] = __shfl(valv, k, 64);
        }
        float4 s = *(const float4*)(emb + (size_t)n * DD + lane * 4);
        float4 e[DEG];
#pragma unroll
        for (int k = 0; k < DEG; ++k)
            e[k] = *(const float4*)(emb + (size_t)cols[k] * DD + lane * 4);
        float a0 = s.x, a1 = s.y, a2 = s.z, a3 = s.w;
#pragma unroll
        for (int k = 0; k < DEG; ++k) {
            float vv = vals[k];
            a0 += vv * e[k].x; a1 += vv * e[k].y;
            a2 += vv * e[k].z; a3 += vv * e[k].w;
        }
        ushort4 o;
        o.x = f2bf(0.5f * a0); o.y = f2bf(0.5f * a1);
        o.z = f2bf(0.5f * a2); o.w = f2bf(0.5f * a3);
        *(ushort4*)(gbf + (size_t)n * DD + lane * 4) = o;
    }
}

// ---------------- L3 (MFMA, 128-row tile) -----------------------------------
__global__ __launch_bounds__(256, 2) void k_scores_mfma(
    const int* __restrict__ items, const ushort* __restrict__ gbf,
    const ushort* __restrict__ w1t, const float* __restrict__ t2,
    const float* __restrict__ at_w0, float* __restrict__ scores)
{
    __shared__ __align__(16) ushort sA[128 * 72];   // 18432 B
    __shared__ __align__(16) ushort sB[256 * 72];   // 36864 B
    __shared__ float sred[128][4];
    __shared__ int s_items[128];
    int tid = threadIdx.x;
    int blk = blockIdx.x;
    int lane = tid & 63, wv = tid >> 6;
    int cn = lane & 15, q = lane >> 4;
    int n0 = wv * 64;

    if (tid < 128) s_items[tid] = items[blk * 128 + tid];
    __syncthreads();

    floatx4 acc[8][4];
#pragma unroll
    for (int mt = 0; mt < 8; ++mt)
#pragma unroll
        for (int nt = 0; nt < 4; ++nt)
            acc[mt][nt] = (floatx4){0.f, 0.f, 0.f, 0.f};

#pragma unroll 1
    for (int kc = 0; kc < 4; ++kc) {
#pragma unroll
        for (int it = 0; it < 4; ++it) {
            int i = tid + it * 256;
            int row = i >> 3, seg = i & 7;
            *(uint4*)(sA + row * 72 + seg * 8) =
                *(const uint4*)(gbf + (size_t)s_items[row] * DD + kc * 64 + seg * 8);
        }
#pragma unroll
        for (int it = 0; it < 8; ++it) {
            int i = tid + it * 256;
            int n = i >> 3, seg = i & 7;
            *(uint4*)(sB + n * 72 + seg * 8) =
                *(const uint4*)(w1t + n * DD + kc * 64 + seg * 8);
        }
        __syncthreads();
#pragma unroll
        for (int ks = 0; ks < 2; ++ks) {
            short8 af[8], bfr[4];
#pragma unroll
            for (int mt = 0; mt < 8; ++mt)
                af[mt] = *(const short8*)(sA + (mt * 16 + cn) * 72 + ks * 32 + q * 8);
#pragma unroll
            for (int nt = 0; nt < 4; ++nt)
                bfr[nt] = *(const short8*)(sB + (n0 + nt * 16 + cn) * 72 + ks * 32 + q * 8);
#pragma unroll
            for (int mt = 0; mt < 8; ++mt)
#pragma unroll
                for (int nt = 0; nt < 4; ++nt)
                    acc[mt][nt] = __builtin_amdgcn_mfma_f32_16x16x32_bf16(
                        af[mt], bfr[nt], acc[mt][nt], 0, 0, 0);
        }
        __syncthreads();
    }

    float w0v[4];
#pragma unroll
    for (int nt = 0; nt < 4; ++nt) w0v[nt] = at_w0[n0 + nt * 16 + cn];
#pragma unroll
    for (int mt = 0; mt < 8; ++mt) {
#pragma unroll
        for (int r = 0; r < 4; ++r) {
            int row_in = q * 4 + r;
            int row = mt * 16 + row_in;
            int b = (blk * 128 + row) / LL;
            const float* t2b = t2 + b * DD;
            float p = 0.f;
#pragma unroll
            for (int nt = 0; nt < 4; ++nt) {
                int col = n0 + nt * 16 + cn;
                float vv = acc[mt][nt][r] + t2b[col];
                p += fmaxf(vv, 0.f) * w0v[nt];
            }
            p += __shfl_xor(p, 1, 64);
            p += __shfl_xor(p, 2, 64);
            p += __shfl_xor(p, 4, 64);
            p += __shfl_xor(p, 8, 64);
            if (cn == 0) sred[row][wv] = p;
        }
    }
    __syncthreads();
    if (tid < 128)
        scores[blk * 128 + tid] = sred[tid][0] + sred[tid][1] + sred[tid][2] + sred[tid][3];
}

__device__ __forceinline__ float pw(float z, float invv) {
    return hw_exp2(invv * hw_log2(z));   // z=0 -> exp2(-inf)=0, correct limit
}

// ---------------- L4: entmax + weighted sum + selu + L2 norm ----------------
__global__ __launch_bounds__(256) void k_entmax_out(
    const float* __restrict__ scores, const float* __restrict__ alpha,
    const int* __restrict__ items, const ushort* __restrict__ gbf,
    float* __restrict__ out)
{
    __shared__ float attn_s[LL];
    __shared__ int s_it[LL];
    __shared__ float red[4];
    int b = blockIdx.x;
    int tid = threadIdx.x;

    if (tid >= 192 && tid < 192 + LL) s_it[tid - 192] = items[b * LL + (tid - 192)];

    if (tid < 64) {
        int l = tid;
        float a = alpha[b];
        float am1 = a - 1.f;
        float invv = 1.f / am1;
        float x = (l < LL) ? scores[b * LL + l] : -__builtin_inff();
        float Xa = x * am1;

        float mx = wave_max64(Xa);
        float tau_lo = mx - 1.f;
        float tau_hi = mx - hw_exp2(am1 * hw_log2(1.f / (float)LL));

        float f_lo = wave_sum64(pw(fmaxf(Xa - tau_lo, 0.f), invv)) - 1.f;

        float dm = tau_hi - tau_lo;
        float tau_m = tau_lo;
#pragma unroll 1
        for (int it = 0; it < NITER; ++it) {
            dm *= 0.5f;
            tau_m = tau_lo + dm;
            // exact early-exit: once dm rounds away, every remaining
            // iteration is a no-op (rounding monotonicity) -> identical result
            if (tau_m == tau_lo) break;
            float f_m = wave_sum64(pw(fmaxf(Xa - tau_m, 0.f), invv)) - 1.f;
            if (f_m * f_lo >= 0.f) tau_lo = tau_m;
        }
        float pm = pw(fmaxf(Xa - tau_m, 0.f), invv);
        float s = wave_sum64(pm);
        if (l < LL) attn_s[l] = pm / s;
    }
    __syncthreads();

    int d = tid;
    float c = 0.f;
#pragma unroll
    for (int l = 0; l < LL; ++l)
        c += attn_s[l] * bf2f(gbf[(size_t)s_it[l] * DD + d]);

    const float SC = 1.0507009873554805f;
    const float AL = 1.6732632423543772f;
    c = SC * (c > 0.f ? c : AL * expm1f(c));

    float ss = wave_sum64(c * c);
    int wv = tid >> 6, lane = tid & 63;
    if (lane == 0) red[wv] = ss;
    __syncthreads();
    float tot = red[0] + red[1] + red[2] + red[3];
    out[b * DD + d] = c / sqrtf(tot);
}

extern "C" void kernel_launch(void* const* d_in, const int* in_sizes, int n_in,
                              void* d_out, int out_size, void* d_ws, size_t ws_size,
                              hipStream_t stream) {
    const int*   items     = (const int*)  d_in[0];
    const float* tgt       = (const float*)d_in[3];
    const float* item_emb  = (const float*)d_in[4];
    const int*   adj_cols  = (const int*)  d_in[6];
    const float* adj_vals  = (const float*)d_in[7];
    const float* wf_w      = (const float*)d_in[8];
    const float* wf_b      = (const float*)d_in[9];
    const float* alphaw_w  = (const float*)d_in[10];
    const float* alphaw_b  = (const float*)d_in[11];
    const float* at_w0     = (const float*)d_in[12];
    const float* at_w1     = (const float*)d_in[13];
    const float* at_w2     = (const float*)d_in[14];
    const float* at_bias   = (const float*)d_in[15];

    const size_t SZ_TAB = (size_t)NN * DD * sizeof(ushort);      // 20.48 MB
    char* ws = (char*)d_ws;
    ushort* gbf = (ushort*)ws;   ws += SZ_TAB;
    ushort* w1t = (ushort*)ws;   ws += (size_t)DD * DD * sizeof(ushort);
    int*   flags = (int*)ws;     ws += (size_t)NN * sizeof(int);
    float* Wc     = (float*)ws;  ws += (size_t)TWO_D * DD * sizeof(float);
    float* bcv    = (float*)ws;  ws += (size_t)DD * sizeof(float);
    float* vv     = (float*)ws;  ws += (size_t)TWO_D * sizeof(float);
    float* c0v    = (float*)ws;  ws += 16 * sizeof(float);
    float* t2     = (float*)ws;  ws += (size_t)BB * DD * sizeof(float);
    float* alpha  = (float*)ws;  ws += ((size_t)BB + 32) * sizeof(float);
    float* scores = (float*)ws;  ws += (size_t)BB * LL * sizeof(float);
    float* out    = (float*)d_out;

    k_stage1<<<712, 256, 0, stream>>>(items, flags,
                                      wf_w, wf_b, at_w2, at_bias,
                                      alphaw_w, alphaw_b, at_w1,
                                      Wc, vv, bcv, c0v, w1t);
    k_stage2<<<11024, 256, 0, stream>>>(item_emb, adj_cols, adj_vals, flags, gbf,
                                        tgt, Wc, bcv, vv, c0v, t2, alpha);
    k_scores_mfma<<<(BB * LL) / 128, 256, 0, stream>>>(items, gbf, w1t, t2, at_w0, scores);
    k_entmax_out<<<BB, 256, 0, stream>>>(scores, alpha, items, gbf, out);
}

// Round 17
// 185.721 us; speedup vs baseline: 1.0808x; 1.0808x over previous
//
#include <hip/hip_runtime.h>
#include <hip/hip_bf16.h>
#include <math.h>

#define BB 1024     // batch
#define LL 50       // sequence length
#define DD 256      // embedding dim
#define TWO_D 512
#define NN 40000    // nodes
#define DEG 12      // neighbors per node (adj_rows = repeat(arange(N), DEG))
#define NITER 50    // entmax bisect iterations

typedef __attribute__((ext_vector_type(8))) short short8;
typedef __attribute__((ext_vector_type(4))) float floatx4;

__device__ __forceinline__ float wave_sum64(float v) {
#pragma unroll
    for (int off = 32; off > 0; off >>= 1) v += __shfl_xor(v, off, 64);
    return v;
}
__device__ __forceinline__ float wave_max64(float v) {
#pragma unroll
    for (int off = 32; off > 0; off >>= 1) v = fmaxf(v, __shfl_xor(v, off, 64));
    return v;
}
__device__ __forceinline__ float bf2f(ushort u) {
    union { unsigned int i; float f; } c; c.i = ((unsigned int)u) << 16; return c.f;
}
__device__ __forceinline__ ushort f2bf(float f) {
    __hip_bfloat16 h = __float2bfloat16(f);
    return *(ushort*)&h;
}
__device__ __forceinline__ float hw_exp2(float x) { return __builtin_amdgcn_exp2f(x); }
__device__ __forceinline__ float hw_log2(float x) { return __builtin_amdgcn_logf(x); }

// ---------------- L1: wprep (tiled) | mark | emb->bf16 ----------------------
// bid [0,512):   k = bid: Wc[k][:] via (dq,ng) tiling — thread (dq,ng) sums a
//   float4 of 4 n-cols over d in [dq*64,dq*64+64) (coalesced float4 at_w2
//   reads, 8-deep MLP), 4-way LDS reduce. v[k] = dot(wf_w[:,k], aw).
//   k<64: w1t transpose cols; k==0: bc, c0.
// bid [512,712): flags[items[i]] = 1 (no zero-init: !=1 only means extra work)
// bid [712,1962): ebf = bf16(item_emb), 8 independent float4 per thread (MLP)
__global__ __launch_bounds__(256) void k_stage1(
    const float* __restrict__ emb, ushort* __restrict__ ebf,
    const int* __restrict__ items, int* __restrict__ flags,
    const float* __restrict__ wf_w, const float* __restrict__ wf_b,
    const float* __restrict__ at_w2, const float* __restrict__ at_bias,
    const float* __restrict__ aw, const float* __restrict__ ab,
    const float* __restrict__ at_w1,
    float* __restrict__ Wc, float* __restrict__ v,
    float* __restrict__ bc, float* __restrict__ c0,
    ushort* __restrict__ w1t)
{
    __shared__ float wcol[DD];
    __shared__ float4 s_p[4][64];
    __shared__ float wred[4];
    __shared__ ushort s_t[4][DD];
    int bid = blockIdx.x;
    int tid = threadIdx.x;

    if (bid < 512) {
        int k = bid;
        int lane = tid & 63, wv = tid >> 6;
        int ng = tid & 63;      // n-group: n = ng*4 .. ng*4+3
        int dq = tid >> 6;      // d-quarter

        wcol[tid] = wf_w[tid * TWO_D + k];
        __syncthreads();

        // 64 d-iterations per thread, float4 across n (coalesced), MLP depth 8
        float4 acc = {0.f, 0.f, 0.f, 0.f};
        const float4* w24 = (const float4*)at_w2;
#pragma unroll 8
        for (int d = dq * 64; d < dq * 64 + 64; ++d) {
            float4 w2 = w24[d * 64 + ng];
            float wc = wcol[d];
            acc.x += wc * w2.x; acc.y += wc * w2.y;
            acc.z += wc * w2.z; acc.w += wc * w2.w;
        }
        s_p[dq][ng] = acc;

        // v[k] while the reduction data settles
        float s1 = wcol[tid] * aw[tid];
        s1 = wave_sum64(s1);
        if (lane == 0) wred[wv] = s1;
        __syncthreads();
        if (tid == 0) v[k] = wred[0] + wred[1] + wred[2] + wred[3];

        if (tid < 64) {
            float4 r0 = s_p[0][tid], r1 = s_p[1][tid];
            float4 r2 = s_p[2][tid], r3 = s_p[3][tid];
            float4 rr;
            rr.x = (r0.x + r1.x) + (r2.x + r3.x);
            rr.y = (r0.y + r1.y) + (r2.y + r3.y);
            rr.z = (r0.z + r1.z) + (r2.z + r3.z);
            rr.w = (r0.w + r1.w) + (r2.w + r3.w);
            *(float4*)(Wc + k * DD + tid * 4) = rr;
        }

        if (k < 64) {
            // transpose 4 columns of at_w1: w1t[t][k0+j] = at_w1[k0+j][t]
            int k0 = k * 4;
#pragma unroll
            for (int j = 0; j < 4; ++j)
                s_t[j][tid] = f2bf(at_w1[(k0 + j) * DD + tid]);
            __syncthreads();
            ushort4 pk;
            pk.x = s_t[0][tid]; pk.y = s_t[1][tid];
            pk.z = s_t[2][tid]; pk.w = s_t[3][tid];
            *(ushort4*)(w1t + tid * DD + k0) = pk;
        }

        if (k == 0) {
            __syncthreads();
            wcol[tid] = wf_b[tid];
            __syncthreads();
            float b[8];
#pragma unroll
            for (int j = 0; j < 8; ++j) b[j] = 0.f;
#pragma unroll 4
            for (int d = 0; d < DD; d += 8) {
#pragma unroll
                for (int j = 0; j < 8; ++j)
                    b[j] += wcol[d + j] * at_w2[(d + j) * DD + tid];
            }
            bc[tid] = at_bias[tid] + ((b[0] + b[1]) + (b[2] + b[3]))
                                   + ((b[4] + b[5]) + (b[6] + b[7]));
            float s2 = wcol[tid] * aw[tid];
            s2 = wave_sum64(s2);
            if (lane == 0) wred[wv] = s2;
            __syncthreads();
            if (tid == 0) c0[0] = wred[0] + wred[1] + wred[2] + wred[3] + ab[0];
        }
    } else if (bid < 712) {
        int i = (bid - 512) * 256 + tid;
        flags[items[i]] = 1;
    } else {
        // 8 independent float4 loads per thread (MLP), coalesced per step
        int base4 = (bid - 712) * (256 * 8) + tid;   // float4 index
        float4 val[8];
#pragma unroll
        for (int j = 0; j < 8; ++j)
            val[j] = *(const float4*)(emb + (size_t)(base4 + j * 256) * 4);
#pragma unroll
        for (int j = 0; j < 8; ++j) {
            ushort4 o;
            o.x = f2bf(val[j].x); o.y = f2bf(val[j].y);
            o.z = f2bf(val[j].z); o.w = f2bf(val[j].w);
            *(ushort4*)(ebf + (size_t)(base4 + j * 256) * 4) = o;
        }
    }
}

// ---------------- L2: t2 direct + alpha | conv (bf16 table) -----------------
// t2a blocks FIRST (long per-block GEMV) so they overlap conv (R13 lesson).
// bid [0,1024): t2[b,n] = tgt[b,:]@Wc[:,n] + bc[n]; ntile==0 emits alpha
// bid [1024,11024): per-node conv from bf16 ebf (one wave per node,
//                   skip unflagged), writes bf16 gbf
__global__ __launch_bounds__(256) void k_stage2(
    const ushort* __restrict__ ebf, const int* __restrict__ adj_cols,
    const float* __restrict__ adj_vals, const int* __restrict__ flags,
    ushort* __restrict__ gbf,
    const float* __restrict__ tgt, const float* __restrict__ Wc,
    const float* __restrict__ bc, const float* __restrict__ v,
    const float* __restrict__ c0, float* __restrict__ t2,
    float* __restrict__ alpha)
{
    __shared__ float x_s[4 * TWO_D];
    int bid = blockIdx.x;
    int tid = threadIdx.x;
    int wv = tid >> 6, lane = tid & 63;

    if (bid < 1024) {
        int t = bid;
        int btile = t >> 2, ntile = t & 3;
        int b0 = btile * 4, n0 = ntile * 64;
        int j = wv;
        for (int i = tid; i < 4 * TWO_D; i += 256) x_s[i] = tgt[b0 * TWO_D + i];
        __syncthreads();

        float acc = bc[n0 + lane];
        const float* xr = x_s + j * TWO_D;
#pragma unroll 8
        for (int k = 0; k < TWO_D; ++k)
            acc += xr[k] * Wc[k * DD + n0 + lane];
        t2[(b0 + j) * DD + n0 + lane] = acc;

        if (ntile == 0) {
            float s = 0.f;
#pragma unroll
            for (int i = 0; i < 8; ++i) s += xr[lane + 64 * i] * v[lane + 64 * i];
            s = wave_sum64(s);
            if (lane == 0) {
                float a = 1.f + 1.f / (1.f + expf(-(s + c0[0])));
                if (a == 1.f) a = 1.00001f;
                alpha[b0 + j] = a;
            }
        }
    } else {
        int n = (bid - 1024) * 4 + wv;
        if (flags[n] != 1) return;
        int colv = 0; float valv = 0.f;
        if (lane < DEG) { colv = adj_cols[n * DEG + lane]; valv = adj_vals[n * DEG + lane]; }
        int cols[DEG]; float vals[DEG];
#pragma unroll
        for (int k = 0; k < DEG; ++k) {
            cols[k] = __shfl(colv, k, 64);
            vals[k] = __shfl(valv, k, 64);
        }
        ushort4 s = *(const ushort4*)(ebf + (size_t)n * DD + lane * 4);
        ushort4 e[DEG];
#pragma unroll
        for (int k = 0; k < DEG; ++k)
            e[k] = *(const ushort4*)(ebf + (size_t)cols[k] * DD + lane * 4);
        float a0 = bf2f(s.x), a1 = bf2f(s.y), a2 = bf2f(s.z), a3 = bf2f(s.w);
#pragma unroll
        for (int k = 0; k < DEG; ++k) {
            float vv = vals[k];
            a0 += vv * bf2f(e[k].x); a1 += vv * bf2f(e[k].y);
            a2 += vv * bf2f(e[k].z); a3 += vv * bf2f(e[k].w);
        }
        ushort4 o;
        o.x = f2bf(0.5f * a0); o.y = f2bf(0.5f * a1);
        o.z = f2bf(0.5f * a2); o.w = f2bf(0.5f * a3);
        *(ushort4*)(gbf + (size_t)n * DD + lane * 4) = o;
    }
}

// ---------------- L3 (MFMA, 128-row tile) -----------------------------------
__global__ __launch_bounds__(256, 2) void k_scores_mfma(
    const int* __restrict__ items, const ushort* __restrict__ gbf,
    const ushort* __restrict__ w1t, const float* __restrict__ t2,
    const float* __restrict__ at_w0, float* __restrict__ scores)
{
    __shared__ __align__(16) ushort sA[128 * 72];   // 18432 B
    __shared__ __align__(16) ushort sB[256 * 72];   // 36864 B
    __shared__ float sred[128][4];
    __shared__ int s_items[128];
    int tid = threadIdx.x;
    int blk = blockIdx.x;
    int lane = tid & 63, wv = tid >> 6;
    int cn = lane & 15, q = lane >> 4;
    int n0 = wv * 64;

    if (tid < 128) s_items[tid] = items[blk * 128 + tid];
    __syncthreads();

    floatx4 acc[8][4];
#pragma unroll
    for (int mt = 0; mt < 8; ++mt)
#pragma unroll
        for (int nt = 0; nt < 4; ++nt)
            acc[mt][nt] = (floatx4){0.f, 0.f, 0.f, 0.f};

#pragma unroll 1
    for (int kc = 0; kc < 4; ++kc) {
#pragma unroll
        for (int it = 0; it < 4; ++it) {
            int i = tid + it * 256;
            int row = i >> 3, seg = i & 7;
            *(uint4*)(sA + row * 72 + seg * 8) =
                *(const uint4*)(gbf + (size_t)s_items[row] * DD + kc * 64 + seg * 8);
        }
#pragma unroll
        for (int it = 0; it < 8; ++it) {
            int i = tid + it * 256;
            int n = i >> 3, seg = i & 7;
            *(uint4*)(sB + n * 72 + seg * 8) =
                *(const uint4*)(w1t + n * DD + kc * 64 + seg * 8);
        }
        __syncthreads();
#pragma unroll
        for (int ks = 0; ks < 2; ++ks) {
            short8 af[8], bfr[4];
#pragma unroll
            for (int mt = 0; mt < 8; ++mt)
                af[mt] = *(const short8*)(sA + (mt * 16 + cn) * 72 + ks * 32 + q * 8);
#pragma unroll
            for (int nt = 0; nt < 4; ++nt)
                bfr[nt] = *(const short8*)(sB + (n0 + nt * 16 + cn) * 72 + ks * 32 + q * 8);
#pragma unroll
            for (int mt = 0; mt < 8; ++mt)
#pragma unroll
                for (int nt = 0; nt < 4; ++nt)
                    acc[mt][nt] = __builtin_amdgcn_mfma_f32_16x16x32_bf16(
                        af[mt], bfr[nt], acc[mt][nt], 0, 0, 0);
        }
        __syncthreads();
    }

    float w0v[4];
#pragma unroll
    for (int nt = 0; nt < 4; ++nt) w0v[nt] = at_w0[n0 + nt * 16 + cn];
#pragma unroll
    for (int mt = 0; mt < 8; ++mt) {
#pragma unroll
        for (int r = 0; r < 4; ++r) {
            int row_in = q * 4 + r;
            int row = mt * 16 + row_in;
            int b = (blk * 128 + row) / LL;
            const float* t2b = t2 + b * DD;
            float p = 0.f;
#pragma unroll
            for (int nt = 0; nt < 4; ++nt) {
                int col = n0 + nt * 16 + cn;
                float vv = acc[mt][nt][r] + t2b[col];
                p += fmaxf(vv, 0.f) * w0v[nt];
            }
            p += __shfl_xor(p, 1, 64);
            p += __shfl_xor(p, 2, 64);
            p += __shfl_xor(p, 4, 64);
            p += __shfl_xor(p, 8, 64);
            if (cn == 0) sred[row][wv] = p;
        }
    }
    __syncthreads();
    if (tid < 128)
        scores[blk * 128 + tid] = sred[tid][0] + sred[tid][1] + sred[tid][2] + sred[tid][3];
}

__device__ __forceinline__ float pw(float z, float invv) {
    return hw_exp2(invv * hw_log2(z));   // z=0 -> exp2(-inf)=0, correct limit
}

// ---------------- L4: entmax + weighted sum + selu + L2 norm ----------------
__global__ __launch_bounds__(256) void k_entmax_out(
    const float* __restrict__ scores, const float* __restrict__ alpha,
    const int* __restrict__ items, const ushort* __restrict__ gbf,
    float* __restrict__ out)
{
    __shared__ float attn_s[LL];
    __shared__ int s_it[LL];
    __shared__ float red[4];
    int b = blockIdx.x;
    int tid = threadIdx.x;

    if (tid >= 192 && tid < 192 + LL) s_it[tid - 192] = items[b * LL + (tid - 192)];

    if (tid < 64) {
        int l = tid;
        float a = alpha[b];
        float am1 = a - 1.f;
        float invv = 1.f / am1;
        float x = (l < LL) ? scores[b * LL + l] : -__builtin_inff();
        float Xa = x * am1;

        float mx = wave_max64(Xa);
        float tau_lo = mx - 1.f;
        float tau_hi = mx - hw_exp2(am1 * hw_log2(1.f / (float)LL));

        float f_lo = wave_sum64(pw(fmaxf(Xa - tau_lo, 0.f), invv)) - 1.f;

        float dm = tau_hi - tau_lo;
        float tau_m = tau_lo;
#pragma unroll 1
        for (int it = 0; it < NITER; ++it) {
            dm *= 0.5f;
            tau_m = tau_lo + dm;
            // exact early-exit: once dm rounds away, every remaining
            // iteration is a no-op (rounding monotonicity) -> identical result
            if (tau_m == tau_lo) break;
            float f_m = wave_sum64(pw(fmaxf(Xa - tau_m, 0.f), invv)) - 1.f;
            if (f_m * f_lo >= 0.f) tau_lo = tau_m;
        }
        float pm = pw(fmaxf(Xa - tau_m, 0.f), invv);
        float s = wave_sum64(pm);
        if (l < LL) attn_s[l] = pm / s;
    }
    __syncthreads();

    int d = tid;
    float c = 0.f;
#pragma unroll
    for (int l = 0; l < LL; ++l)
        c += attn_s[l] * bf2f(gbf[(size_t)s_it[l] * DD + d]);

    const float SC = 1.0507009873554805f;
    const float AL = 1.6732632423543772f;
    c = SC * (c > 0.f ? c : AL * expm1f(c));

    float ss = wave_sum64(c * c);
    int wv = tid >> 6, lane = tid & 63;
    if (lane == 0) red[wv] = ss;
    __syncthreads();
    float tot = red[0] + red[1] + red[2] + red[3];
    out[b * DD + d] = c / sqrtf(tot);
}

extern "C" void kernel_launch(void* const* d_in, const int* in_sizes, int n_in,
                              void* d_out, int out_size, void* d_ws, size_t ws_size,
                              hipStream_t stream) {
    const int*   items     = (const int*)  d_in[0];
    const float* tgt       = (const float*)d_in[3];
    const float* item_emb  = (const float*)d_in[4];
    const int*   adj_cols  = (const int*)  d_in[6];
    const float* adj_vals  = (const float*)d_in[7];
    const float* wf_w      = (const float*)d_in[8];
    const float* wf_b      = (const float*)d_in[9];
    const float* alphaw_w  = (const float*)d_in[10];
    const float* alphaw_b  = (const float*)d_in[11];
    const float* at_w0     = (const float*)d_in[12];
    const float* at_w1     = (const float*)d_in[13];
    const float* at_w2     = (const float*)d_in[14];
    const float* at_bias   = (const float*)d_in[15];

    const size_t SZ_TAB = (size_t)NN * DD * sizeof(ushort);      // 20.48 MB
    char* ws = (char*)d_ws;
    ushort* gbf = (ushort*)ws;   ws += SZ_TAB;
    ushort* ebf = (ushort*)ws;   ws += SZ_TAB;
    ushort* w1t = (ushort*)ws;   ws += (size_t)DD * DD * sizeof(ushort);
    int*   flags = (int*)ws;     ws += (size_t)NN * sizeof(int);
    float* Wc     = (float*)ws;  ws += (size_t)TWO_D * DD * sizeof(float);
    float* bcv    = (float*)ws;  ws += (size_t)DD * sizeof(float);
    float* vv     = (float*)ws;  ws += (size_t)TWO_D * sizeof(float);
    float* c0v    = (float*)ws;  ws += 16 * sizeof(float);
    float* t2     = (float*)ws;  ws += (size_t)BB * DD * sizeof(float);
    float* alpha  = (float*)ws;  ws += ((size_t)BB + 32) * sizeof(float);
    float* scores = (float*)ws;  ws += (size_t)BB * LL * sizeof(float);
    float* out    = (float*)d_out;

    k_stage1<<<1962, 256, 0, stream>>>(item_emb, ebf, items, flags,
                                       wf_w, wf_b, at_w2, at_bias,
                                       alphaw_w, alphaw_b, at_w1,
                                       Wc, vv, bcv, c0v, w1t);
    k_stage2<<<11024, 256, 0, stream>>>(ebf, adj_cols, adj_vals, flags, gbf,
                                        tgt, Wc, bcv, vv, c0v, t2, alpha);
    k_scores_mfma<<<(BB * LL) / 128, 256, 0, stream>>>(items, gbf, w1t, t2, at_w0, scores);
    k_entmax_out<<<BB, 256, 0, stream>>>(scores, alpha, items, gbf, out);
}